// Round 12
// baseline (2357.848 us; speedup 1.0000x reference)
//
#include <hip/hip_runtime.h>

// LSTMCharacterPredictor — round 12: counter-detect + tagless bf16 channel.
// T=512 B=64 E=512 H=1024 V=256.
// R11 post-mortem: AGPR W residency works but small (+6%) -> detection is the
// period. New model: data-polling reads 32KB/block/round => ~10TB/s of MALL
// traffic self-congests rounds to ~1us; detection granularity = round time.
// Fix: per-(step,group) arrival counter (one broadcast line to poll), h goes
// tagless through outs[] itself (distinct addr per t: no ring/ABA/unpack).
// Producer: store h -> vmcnt(0) -> barrier -> tid0 atomic_add(cnt[t][g]).
// Consumer: spin one dword until >=32 -> single full h load -> MFMA.
// Base: R10 8-wave topology + R11 AGPR-pinned W (128 AGPR/wave).

#define TT 512
#define BB 64
#define HH 1024
#define VV 256
#define EE 512
#define SPIN_CAP 4096

typedef __attribute__((ext_vector_type(8))) short bf16x8;
typedef __attribute__((ext_vector_type(4))) float f32x4;
typedef __attribute__((ext_vector_type(4))) int i32x4;
typedef __attribute__((ext_vector_type(4))) unsigned short u16x4;

static __device__ __forceinline__ unsigned short f2bf(float f) {
  union { float f; unsigned u; } x; x.f = f;
  unsigned r = x.u + 0x7fffu + ((x.u >> 16) & 1u);   // RNE
  return (unsigned short)(r >> 16);
}

// ---------------- f32 -> bf16 convert (vectorized) ----------------
__global__ void cvt_bf16(const float* __restrict__ s, unsigned short* __restrict__ d, int n4) {
  int i = blockIdx.x * blockDim.x + threadIdx.x;
  int st = gridDim.x * blockDim.x;
  for (; i < n4; i += st) {
    f32x4 v = *(const f32x4*)(s + 4l * i);
    u16x4 o;
    o.x = f2bf(v.x); o.y = f2bf(v.y); o.z = f2bf(v.z); o.w = f2bf(v.w);
    *(u16x4*)(d + 4l * i) = o;
  }
}

// ------- proj packed: proj[v][unit][gate] = enc@W_ih^T + b_ih + b_hh -------
__global__ __launch_bounds__(256) void proj_kernel(
    const unsigned short* __restrict__ A,    // enc bf16 [256][512]
    const unsigned short* __restrict__ Wi,   // W_ih bf16 [4096][512]
    const float* __restrict__ bih, const float* __restrict__ bhh,
    float* __restrict__ proj)                // [256][1024][4] f32
{
  __shared__ __align__(16) unsigned char Asm[64 * 128];   // [64 m][64 k] bf16, swizzled
  const int tid = threadIdx.x;
  const int w = tid >> 6;
  const int lane = tid & 63;
  const int ln = lane & 15, kg = lane >> 4;
  const int m0 = blockIdx.x * 64;            // 4 blocks
  const int nb = blockIdx.y * 256 + w * 64;  // 16 blocks.y, wave owns 64 n
  const int srow = tid >> 2, skq = tid & 3;

  f32x4 acc[4][4];
  for (int a = 0; a < 4; ++a) for (int b = 0; b < 4; ++b) acc[a][b] = (f32x4){0.f,0.f,0.f,0.f};

  for (int kc = 0; kc < 8; ++kc) {           // K=512 in chunks of 64
    {
      const unsigned short* src = A + (m0 + srow) * 512 + kc * 64 + skq * 16;
      unsigned base = (unsigned)(srow * 128 + skq * 32);
      unsigned sw = (unsigned)((srow & 7) << 4);
      *(i32x4*)(Asm + ((base) ^ sw))      = *(const i32x4*)(src);
      *(i32x4*)(Asm + ((base + 16) ^ sw)) = *(const i32x4*)(src + 8);
    }
    __syncthreads();
    for (int kk = 0; kk < 2; ++kk) {
      bf16x8 afr[4];
      for (int mi = 0; mi < 4; ++mi) {
        int row = mi * 16 + ln;
        unsigned off = (unsigned)(row * 128 + (kk * 32 + kg * 8) * 2);
        afr[mi] = *(const bf16x8*)(Asm + (off ^ ((unsigned)(row & 7) << 4)));
      }
      for (int ni = 0; ni < 4; ++ni) {
        const unsigned short* bp = Wi + (nb + ni * 16 + ln) * 512 + kc * 64 + kk * 32 + kg * 8;
        bf16x8 bfr = *(const bf16x8*)bp;
        for (int mi = 0; mi < 4; ++mi)
          acc[mi][ni] = __builtin_amdgcn_mfma_f32_16x16x32_bf16(afr[mi], bfr, acc[mi][ni], 0, 0, 0);
      }
    }
    __syncthreads();
  }
  for (int ni = 0; ni < 4; ++ni) {
    int nn = nb + ni * 16 + ln;             // global gate-row = gi*1024 + unit
    int gi = nn >> 10, uu = nn & 1023;
    float bias = bih[nn] + bhh[nn];
    for (int mi = 0; mi < 4; ++mi) {
      int mr = m0 + mi * 16 + kg * 4;
      for (int r = 0; r < 4; ++r)
        proj[(size_t)(mr + r) * 4096 + uu * 4 + gi] = acc[mi][ni][r] + bias;
    }
  }
}

// ---------------- persistent LSTM scan (counter-detect, tagless) ----------------
// group g=blk&7 owns samples [g*8,+8); slice r=blk>>3 owns units [r*32,+32).
// 512 thr / 8 waves; wave w: K-slice [w*128,+128), bw[8][4] in AGPRs.
// Channel: outs[t][sample][unit] bf16 (distinct addr per t -> no ABA).
// cnt[t][g]: producers atomically count completed publishes of h(t).
__global__ __launch_bounds__(512, 2) void scan_kernel(
    const unsigned short* __restrict__ Whh,   // bf16 [4096][1024]
    const float* __restrict__ proj,           // [256][1024][4] f32 packed
    const int* __restrict__ ints,             // [512][64]
    const float* __restrict__ h0v,            // output0 [1024]
    const float* __restrict__ c0v,            // memory0 [1024]
    unsigned int* __restrict__ cnt,           // [512][8] arrival counters
    unsigned short* __restrict__ outs)        // bf16 [512][64][1024] h history
{
  __shared__ float gatesm[8 * 8 * 128];       // [wave][sample(8)][localrow(128)] 32 KB

  const int tid = threadIdx.x;
  const int blk = blockIdx.x;
  const int g = blk & 7, r = blk >> 3;        // XCD-affine heuristic mapping
  const int w = tid >> 6, lane = tid & 63;
  const int ln = lane & 15, kg = lane >> 4;
  const int s = (tid & 255) >> 5, u = tid & 31;  // elementwise cell (tid<256)
  const int sg = g * 8 + s;
  const int ug = r * 32 + u;

  // W_hh B-frags: local gate-row lrow=nt*16+ln -> global row
  // (lrow>>5)*1024 + r*32 + (lrow&31); k = w*128 + kt*32 + kg*8 + [0,8).
  bf16x8 bw[8][4];
#pragma unroll
  for (int nt = 0; nt < 8; ++nt) {
    int lrow = nt * 16 + ln;
    int grow = (lrow >> 5) * 1024 + r * 32 + (lrow & 31);
    const unsigned short* wp = Whh + (size_t)grow * 1024 + w * 128 + kg * 8;
#pragma unroll
    for (int kt = 0; kt < 4; ++kt)
      bw[nt][kt] = *(const bf16x8*)(wp + kt * 32);
  }
  // pin into AGPRs (separate RA class; MFMA reads B directly from AGPR)
#pragma unroll
  for (int nt = 0; nt < 8; ++nt)
#pragma unroll
    for (int kt = 0; kt < 4; ++kt)
      asm volatile("" : "+a"(bw[nt][kt]));

  float c = (tid < 256) ? c0v[ug] : 0.f;

  // publish h0 -> outs[0]; count arrival
  if (tid < 256) {
    unsigned short hb = f2bf(h0v[ug]);
    unsigned short* hp = outs + (size_t)sg * 1024 + ug;
    asm volatile("global_store_short %0, %1, off sc0 sc1" :: "v"(hp), "v"((unsigned)hb) : "memory");
  }
  asm volatile("s_waitcnt vmcnt(0)" ::: "memory");
  __syncthreads();
  if (tid == 0)
    __hip_atomic_fetch_add(&cnt[g], 1u, __ATOMIC_RELAXED, __HIP_MEMORY_SCOPE_AGENT);

  // prefetch proj row for t=0
  f32x4 prv = (f32x4){0.f,0.f,0.f,0.f};
  if (tid < 256) {
    int vocab = ints[sg];
    prv = *(const f32x4*)(proj + (size_t)vocab * 4096 + ug * 4);
  }

  for (int t = 0; t < TT - 1; ++t) {
    // ---- detect: spin on ONE broadcast dword until all 32 producers arrived ----
    {
      int guard = 0;
      while (__hip_atomic_load(&cnt[t * 8 + g], __ATOMIC_RELAXED, __HIP_MEMORY_SCOPE_AGENT) < 32u) {
        if (++guard > SPIN_CAP) break;        // deadlock escape (never legit)
      }
    }
    __builtin_amdgcn_sched_barrier(0);

    // ---- single full h load: lane row (ln&7), wave k-slice; bf16 direct ----
    bf16x8 av[4];
    {
      const unsigned short* ab = outs + (size_t)(t * 64 + g * 8 + (ln & 7)) * 1024
                               + w * 128 + kg * 8;
#define LA(i, off_lit) \
      asm volatile("global_load_dwordx4 %0, %1, off offset:" off_lit " sc0 sc1" \
                   : "=v"(av[i]) : "v"(ab) : "memory")
      LA(0, "0"); LA(1, "64"); LA(2, "128"); LA(3, "192");
#undef LA
      asm volatile("s_waitcnt vmcnt(0)" ::: "memory");
      __builtin_amdgcn_sched_barrier(0);      // rule 18: keep MFMA after wait
    }

    // ---- 32 MFMAs/wave (8 independent n-tile chains, B from AGPR) ----
    f32x4 acc[8];
#pragma unroll
    for (int i = 0; i < 8; ++i) acc[i] = (f32x4){0.f,0.f,0.f,0.f};
#pragma unroll
    for (int kt = 0; kt < 4; ++kt)
#pragma unroll
      for (int nt = 0; nt < 8; ++nt)
        acc[nt] = __builtin_amdgcn_mfma_f32_16x16x32_bf16(av[kt], bw[nt][kt], acc[nt], 0, 0, 0);

    // ---- partials to LDS: m=kg*4+rr (sample, keep m<8), n=nt*16+ln ----
#pragma unroll
    for (int nt = 0; nt < 8; ++nt) {
      if (kg < 2) {
#pragma unroll
        for (int rr = 0; rr < 4; ++rr)
          gatesm[(w * 8 + kg * 4 + rr) * 128 + nt * 16 + ln] = acc[nt][rr];
      }
    }
    __syncthreads();

    // ---- elementwise cell update + publish (tid<256, thread (s,u)) ----
    if (tid < 256) {
      float g0 = prv.x, g1 = prv.y, g2 = prv.z, g3 = prv.w;
#pragma unroll
      for (int ww = 0; ww < 8; ++ww) {
        const float* gm = gatesm + (ww * 8 + s) * 128 + u;
        g0 += gm[0];     // gate i
        g1 += gm[32];    // gate f
        g2 += gm[64];    // gate g
        g3 += gm[96];    // gate o
      }
      float ii = __builtin_amdgcn_rcpf(1.f + __expf(-g0));
      float ff = __builtin_amdgcn_rcpf(1.f + __expf(-g1));
      float gt = 1.f - 2.f * __builtin_amdgcn_rcpf(1.f + __expf(2.f * g2));
      float oo = __builtin_amdgcn_rcpf(1.f + __expf(-g3));
      c = ff * c + ii * gt;
      float hv = oo * (1.f - 2.f * __builtin_amdgcn_rcpf(1.f + __expf(2.f * c)));

      unsigned short hb = f2bf(hv);
      unsigned short* hp = outs + (size_t)((t + 1) * 64 + sg) * 1024 + ug;
      asm volatile("global_store_short %0, %1, off sc0 sc1" :: "v"(hp), "v"((unsigned)hb) : "memory");

      // prefetch next step's proj row (overlaps store drain + next detect)
      if (t + 1 < TT - 1) {
        int vocab = ints[(t + 1) * 64 + sg];
        prv = *(const f32x4*)(proj + (size_t)vocab * 4096 + ug * 4);
      }
    }
    // drain own h store (and prefetch) before signaling arrival
    asm volatile("s_waitcnt vmcnt(0)" ::: "memory");
    __syncthreads();   // all waves' stores drained + gatesm WAR guard
    if (tid == 0)
      __hip_atomic_fetch_add(&cnt[(t + 1) * 8 + g], 1u, __ATOMIC_RELAXED, __HIP_MEMORY_SCOPE_AGENT);
  }
}

// ---------------- decode: out[32768,256] = outs_bf @ W_dec^T + b_dec ----------------
__global__ __launch_bounds__(256) void decode_kernel(
    const unsigned short* __restrict__ A,    // outs bf16 [32768][1024]
    const unsigned short* __restrict__ Wd,   // W_dec bf16 [256][1024]
    const float* __restrict__ bdec,
    float* __restrict__ out)                 // [32768][256]
{
  __shared__ __align__(16) unsigned char Asm[64 * 128];
  const int tid = threadIdx.x;
  const int w = tid >> 6;
  const int lane = tid & 63;
  const int ln = lane & 15, kg = lane >> 4;
  const int m0 = blockIdx.x * 64;
  const int nb = w * 64;                     // 4 waves cover N=256
  const int srow = tid >> 2, skq = tid & 3;

  f32x4 acc[4][4];
  for (int a = 0; a < 4; ++a) for (int b = 0; b < 4; ++b) acc[a][b] = (f32x4){0.f,0.f,0.f,0.f};

  for (int kc = 0; kc < 16; ++kc) {          // K=1024 in chunks of 64
    {
      const unsigned short* src = A + (m0 + srow) * 1024 + kc * 64 + skq * 16;
      unsigned base = (unsigned)(srow * 128 + skq * 32);
      unsigned sw = (unsigned)((srow & 7) << 4);
      *(i32x4*)(Asm + ((base) ^ sw))      = *(const i32x4*)(src);
      *(i32x4*)(Asm + ((base + 16) ^ sw)) = *(const i32x4*)(src + 8);
    }
    __syncthreads();
    for (int kk = 0; kk < 2; ++kk) {
      bf16x8 afr[4];
      for (int mi = 0; mi < 4; ++mi) {
        int row = mi * 16 + ln;
        unsigned off = (unsigned)(row * 128 + (kk * 32 + kg * 8) * 2);
        afr[mi] = *(const bf16x8*)(Asm + (off ^ ((unsigned)(row & 7) << 4)));
      }
      for (int ni = 0; ni < 4; ++ni) {
        const unsigned short* bp = Wd + (nb + ni * 16 + ln) * 1024 + kc * 64 + kk * 32 + kg * 8;
        bf16x8 bfr = *(const bf16x8*)bp;
        for (int mi = 0; mi < 4; ++mi)
          acc[mi][ni] = __builtin_amdgcn_mfma_f32_16x16x32_bf16(afr[mi], bfr, acc[mi][ni], 0, 0, 0);
      }
    }
    __syncthreads();
  }
  for (int ni = 0; ni < 4; ++ni) {
    int nn = nb + ni * 16 + ln;
    float bd = bdec[nn];
    for (int mi = 0; mi < 4; ++mi) {
      int mr = m0 + mi * 16 + kg * 4;
      for (int r = 0; r < 4; ++r)
        out[(mr + r) * 256 + nn] = acc[mi][ni][r] + bd;
    }
  }
}

// ---------------- host ----------------
extern "C" void kernel_launch(void* const* d_in, const int* in_sizes, int n_in,
                              void* d_out, int out_size, void* d_ws, size_t ws_size,
                              hipStream_t stream) {
  const int*   ints = (const int*)  d_in[0];
  const float* enc  = (const float*)d_in[1];
  const float* out0 = (const float*)d_in[2];
  const float* mem0 = (const float*)d_in[3];
  const float* Wih  = (const float*)d_in[4];
  const float* Whh  = (const float*)d_in[5];
  const float* bih  = (const float*)d_in[6];
  const float* bhh  = (const float*)d_in[7];
  const float* Wdec = (const float*)d_in[8];
  const float* bdec = (const float*)d_in[9];
  float* out = (float*)d_out;

  char* ws = (char*)d_ws;
  size_t off = 0;
  auto alloc = [&](size_t bytes) { char* p = ws + off; off += (bytes + 255) & ~(size_t)255; return p; };
  unsigned short* Whh_bf  = (unsigned short*)alloc(4096ull * 1024 * 2);     // 8 MB
  unsigned short* enc_bf  = (unsigned short*)alloc(256ull * 512 * 2);
  unsigned short* Wih_bf  = (unsigned short*)alloc(4096ull * 512 * 2);      // 4 MB
  unsigned short* Wdec_bf = (unsigned short*)alloc(256ull * 1024 * 2);
  float*          proj    = (float*)alloc(256ull * 4096 * 4);               // 4 MB packed
  unsigned short* outs_bf = (unsigned short*)alloc(512ull * 64 * 1024 * 2); // 64 MB
  unsigned int*   cnt     = (unsigned int*)alloc(512ull * 8 * 4);           // 16 KB
  // total ~81 MB of ws

  // Zero arrival counters every launch (first call sees recycled ws garbage).
  hipMemsetAsync(cnt, 0, 512ull * 8 * 4, stream);

  cvt_bf16<<<512, 256, 0, stream>>>(Whh,  Whh_bf,  4096 * 1024 / 4);
  cvt_bf16<<<64,  256, 0, stream>>>(enc,  enc_bf,  256 * 512 / 4);
  cvt_bf16<<<256, 256, 0, stream>>>(Wih,  Wih_bf,  4096 * 512 / 4);
  cvt_bf16<<<64,  256, 0, stream>>>(Wdec, Wdec_bf, 256 * 1024 / 4);

  proj_kernel<<<dim3(4, 16), 256, 0, stream>>>(enc_bf, Wih_bf, bih, bhh, proj);

  {
    const unsigned short* a0 = Whh_bf;
    const float* a1 = proj;
    const int* a2 = ints;
    const float* a3 = out0;
    const float* a4 = mem0;
    unsigned int* a5 = cnt;
    unsigned short* a6 = outs_bf;
    void* args[] = { &a0, &a1, &a2, &a3, &a4, &a5, &a6 };
    hipError_t e = hipLaunchCooperativeKernel((const void*)scan_kernel,
                                              dim3(256), dim3(512), args, 0, stream);
    if (e != hipSuccess) {
      // fallback: plain launch; 512 thr, ~110 VGPR + 128 AGPR -> 1 blk/CU
      scan_kernel<<<256, 512, 0, stream>>>(Whh_bf, proj, ints, out0, mem0,
                                           cnt, outs_bf);
    }
  }

  decode_kernel<<<512, 256, 0, stream>>>(outs_bf, Wdec_bf, bdec, out);
}